// Round 11
// baseline (1577.881 us; speedup 1.0000x reference)
//
#include <hip/hip_runtime.h>

// ---------------------------------------------------------------------------
// GCN 2-layer forward, round 23.
// Round-22 post-mortem: NEUTRAL 200.8 (4-edge pipeline null) -> agg is NOT
// thread-latency-bound; fabric random-gather rate (~2.25TB/s, FETCH 90MB =
// 7.1 XCDs x 12.8MB structural model) is the wall. Agg ~40us each is fixed.
// Remaining addressable block: bfill + CSR machinery (~15us + 20MB traffic).
// Round-23 delta: DELETE the CSR. Block-per-bucket agg:
//   * k_agg: read bucket's UNSORTED pairs segment (coalesced), gather H[r]
//     (unchanged, irreducible), atomicAdd 64 feats into LDS acc[256][65]
//     (stride 65 -> ~2-way conflicts; ~6us LDS + ~11us VALU hide under the
//     40us fabric wall), then coalesced 128B-row writeout.
//   * k_deg: per-bucket histogram -> dinv (replaces bfill, ~3us).
//   * csrc/cnt/offsets/padding deleted. Sum order becomes atomic-arrival
//     (nondeterministic) -> absmax may shift slightly; watched.
// Pipeline: [count||gemm1], scan, scatter, deg, agg1, gemm2, agg2.
// ---------------------------------------------------------------------------

#define BSH 8        // bucket shift: 256 nodes per bucket
#define BSZ 256
#define PTILE 4096   // messages per partition tile
#define CAP 6144     // fixed bucket capacity (slots)
#define GEMMB 1024   // gemm1 blocks inside k_cntgm

typedef __attribute__((ext_vector_type(8))) short bf16x8;
typedef __attribute__((ext_vector_type(4))) float f32x4;

__device__ __forceinline__ unsigned bf16_rne(float f) {
    unsigned b = __float_as_uint(f);
    return (b + 0x7fffu + ((b >> 16) & 1u)) >> 16;
}
__device__ __forceinline__ float bf16_lo(unsigned u) { return __uint_as_float(u << 16); }
__device__ __forceinline__ float bf16_hi(unsigned u) { return __uint_as_float(u & 0xffff0000u); }

// H[row] = (X[row] @ W) UNSCALED, bf16 out; zero sentinel row at N.
template <bool BF16IN, int NT>
__device__ __forceinline__ void gemm_body(const void* __restrict__ Xv,
                                          const float* __restrict__ W,
                                          unsigned* __restrict__ Hout,
                                          int N, int nSlabs, int blkLocal,
                                          int nBlkLocal, float* SMEM) {
    int t = threadIdx.x;
    int lane = t & 63, w = t >> 6;
    int nn = lane & 15, kq = lane >> 4;
    constexpr int NW = NT / 64;

    for (int i = t; i < 1024; i += NT) ((float4*)SMEM)[i] = ((const float4*)W)[i];
    __syncthreads();
    bf16x8 Bf[2][4];
    #pragma unroll
    for (int kt = 0; kt < 2; kt++) {
        #pragma unroll
        for (int ct = 0; ct < 4; ct++) {
            union { bf16x8 v; unsigned short s[8]; } u;
            #pragma unroll
            for (int j = 0; j < 8; j++) {
                int k = kt * 32 + kq * 8 + j;
                u.s[j] = (unsigned short)bf16_rne(SMEM[k * 64 + ct * 16 + nn]);
            }
            Bf[kt][ct] = u.v;
        }
    }
    __syncthreads();  // W region dead; SMEM becomes per-wave transpose scratch

    float* outT = SMEM + w * 1056;  // 16 rows x 66 floats

    for (int slab = blkLocal * NW + w; slab < nSlabs; slab += nBlkLocal * NW) {
        int row0 = slab * 16;
        int rowA = min(row0 + nn, N - 1);
        bf16x8 A0, A1;
        if (BF16IN) {
            const uint4* X = (const uint4*)Xv;  // row = 8 uint4
            union { uint4 u; bf16x8 v; } a0, a1;
            a0.u = X[(size_t)rowA * 8 + kq];
            a1.u = X[(size_t)rowA * 8 + 4 + kq];
            A0 = a0.v; A1 = a1.v;
        } else {
            const float4* X = (const float4*)Xv;  // row = 16 float4
            float4 f0 = X[(size_t)rowA * 16 + kq * 2];
            float4 f1 = X[(size_t)rowA * 16 + kq * 2 + 1];
            float4 f2 = X[(size_t)rowA * 16 + 8 + kq * 2];
            float4 f3 = X[(size_t)rowA * 16 + 8 + kq * 2 + 1];
            union { bf16x8 v; unsigned short s[8]; } a0, a1;
            a0.s[0] = (unsigned short)bf16_rne(f0.x); a0.s[1] = (unsigned short)bf16_rne(f0.y);
            a0.s[2] = (unsigned short)bf16_rne(f0.z); a0.s[3] = (unsigned short)bf16_rne(f0.w);
            a0.s[4] = (unsigned short)bf16_rne(f1.x); a0.s[5] = (unsigned short)bf16_rne(f1.y);
            a0.s[6] = (unsigned short)bf16_rne(f1.z); a0.s[7] = (unsigned short)bf16_rne(f1.w);
            a1.s[0] = (unsigned short)bf16_rne(f2.x); a1.s[1] = (unsigned short)bf16_rne(f2.y);
            a1.s[2] = (unsigned short)bf16_rne(f2.z); a1.s[3] = (unsigned short)bf16_rne(f2.w);
            a1.s[4] = (unsigned short)bf16_rne(f3.x); a1.s[5] = (unsigned short)bf16_rne(f3.y);
            a1.s[6] = (unsigned short)bf16_rne(f3.z); a1.s[7] = (unsigned short)bf16_rne(f3.w);
            A0 = a0.v; A1 = a1.v;
        }

        f32x4 acc[4];
        #pragma unroll
        for (int ct = 0; ct < 4; ct++) acc[ct] = (f32x4){0.f, 0.f, 0.f, 0.f};
        #pragma unroll
        for (int ct = 0; ct < 4; ct++) {
            acc[ct] = __builtin_amdgcn_mfma_f32_16x16x32_bf16(A0, Bf[0][ct], acc[ct], 0, 0, 0);
            acc[ct] = __builtin_amdgcn_mfma_f32_16x16x32_bf16(A1, Bf[1][ct], acc[ct], 0, 0, 0);
        }

        #pragma unroll
        for (int reg = 0; reg < 4; reg++) {
            int r = kq * 4 + reg;
            #pragma unroll
            for (int ct = 0; ct < 4; ct++) {
                outT[r * 66 + ct * 16 + nn] = acc[ct][reg];
            }
        }
        int rr = lane >> 2;
        int c0 = (lane & 3) * 16;
        int orow = row0 + rr;
        if (orow < N) {
            unsigned pk[8];
            #pragma unroll
            for (int i = 0; i < 8; i++) {
                float lo = outT[rr * 66 + c0 + 2 * i];
                float hi = outT[rr * 66 + c0 + 2 * i + 1];
                pk[i] = bf16_rne(lo) | (bf16_rne(hi) << 16);
            }
            uint4* dst = (uint4*)Hout + (size_t)orow * 8 + (lane & 3) * 2;
            dst[0] = make_uint4(pk[0], pk[1], pk[2], pk[3]);
            dst[1] = make_uint4(pk[4], pk[5], pk[6], pk[7]);
        } else if (orow == N) {  // zero sentinel row
            uint4* dst = (uint4*)Hout + (size_t)N * 8 + (lane & 3) * 2;
            dst[0] = make_uint4(0, 0, 0, 0);
            dst[1] = make_uint4(0, 0, 0, 0);
        }
    }
}

// Fused: per-tile bucket histogram (blocks < numTiles) || gemm1 (next GEMMB).
__global__ __launch_bounds__(512) void k_cntgm(const int* __restrict__ coli,
                                               int E, int N, int NB, int numTiles,
                                               int* __restrict__ tcnt,
                                               const float* __restrict__ x,
                                               const float* __restrict__ W1,
                                               unsigned* __restrict__ hbuf,
                                               int nSlabs) {
    __shared__ float SMEM[8448];  // gemm: W + 8-wave scratch; count: hist
    int bid = blockIdx.x;
    if (bid >= numTiles) {
        gemm_body<false, 512>(x, W1, hbuf, N, nSlabs, bid - numTiles, GEMMB, SMEM);
        return;
    }
    int* hist = (int*)SMEM;
    int t = threadIdx.x;
    int T = E + N;
    int tstart = bid * PTILE;
    int m = min(PTILE, T - tstart);
    for (int b = t; b < NB; b += 512) hist[b] = 0;
    __syncthreads();
    for (int i = t; i < m; i += 512) {
        int g = tstart + i;
        int c = (g < E) ? coli[g] : (g - E);
        atomicAdd(&hist[c >> BSH], 1);
    }
    __syncthreads();
    for (int b = t; b < NB; b += 512) tcnt[(size_t)bid * NB + b] = hist[b];
}

// Block-per-bucket exclusive scan over tiles (chunked, wave-shuffle).
__global__ __launch_bounds__(512) void k_scan(int* __restrict__ tcnt,
                                              int* __restrict__ btot,
                                              int NB, int numTiles) {
    __shared__ int wsum[8];
    int b = blockIdx.x;
    int t = threadIdx.x;
    int lane = t & 63, wid = t >> 6;
    int base = 0;
    for (int c0 = 0; c0 < numTiles; c0 += 512) {
        int tt = c0 + t;
        int v = (tt < numTiles) ? tcnt[(size_t)tt * NB + b] : 0;
        int inc = v;
        #pragma unroll
        for (int d = 1; d < 64; d <<= 1) {
            int o = __shfl_up(inc, d);
            if (lane >= d) inc += o;
        }
        if (lane == 63) wsum[wid] = inc;
        __syncthreads();
        int woff = 0, ctot = 0;
        #pragma unroll
        for (int i = 0; i < 8; i++) {
            int s = wsum[i];
            if (i < wid) woff += s;
            ctot += s;
        }
        if (tt < numTiles) tcnt[(size_t)tt * NB + b] = b * CAP + base + woff + inc - v;
        base += ctot;
        __syncthreads();
    }
    if (t == 0) btot[b] = base;
}

// Scatter: LDS counting sort per tile, coalesced pairs writes.
// pairs payload: r | (node-in-bucket << 24).
__global__ __launch_bounds__(512) void k_scatter(const int* __restrict__ rowi,
                                                 const int* __restrict__ coli,
                                                 int E, int N, int NB, int numTiles,
                                                 const int* __restrict__ tcnt,
                                                 unsigned* __restrict__ pairs) {
    __shared__ int hist[512];
    __shared__ int lbase[512];
    __shared__ int gbase[512];
    __shared__ unsigned sorted[PTILE];
    __shared__ unsigned short sbkt[PTILE];
    __shared__ int wsum[8];
    int t = threadIdx.x;
    int T = E + N;
    int tile = blockIdx.x;
    int tstart = tile * PTILE;
    int m = min(PTILE, T - tstart);
    int lane = t & 63, wid = t >> 6;
    for (int b = t; b < NB; b += 512) {
        hist[b] = 0;
        gbase[b] = tcnt[(size_t)tile * NB + b];
    }
    __syncthreads();
    int c_reg[8];
    #pragma unroll
    for (int k = 0; k < 8; k++) {
        int i = t + k * 512;
        int c = 0;
        if (i < m) {
            int g = tstart + i;
            c = (g < E) ? coli[g] : (g - E);
            atomicAdd(&hist[c >> BSH], 1);
        }
        c_reg[k] = c;
    }
    __syncthreads();
    {   // block exclusive scan of hist -> lbase
        int v = (t < NB) ? hist[t] : 0;
        int inc = v;
        #pragma unroll
        for (int d = 1; d < 64; d <<= 1) {
            int o = __shfl_up(inc, d);
            if (lane >= d) inc += o;
        }
        if (lane == 63) wsum[wid] = inc;
        __syncthreads();
        int woff = 0;
        for (int i = 0; i < wid; i++) woff += wsum[i];
        if (t < NB) lbase[t] = woff + inc - v;
        __syncthreads();
    }
    for (int b = t; b < NB; b += 512) hist[b] = 0;  // reuse as cursors
    __syncthreads();
    #pragma unroll
    for (int k = 0; k < 8; k++) {
        int i = t + k * 512;
        if (i < m) {
            int g = tstart + i;
            int c = c_reg[k];
            int r = (g < E) ? rowi[g] : c;  // self-loop tail has r == c
            int b = c >> BSH;
            int lr = atomicAdd(&hist[b], 1);
            int pos = lbase[b] + lr;
            sorted[pos] = (unsigned)r | ((unsigned)(c & (BSZ - 1)) << 24);
            sbkt[pos] = (unsigned short)b;
        }
    }
    __syncthreads();
    for (int j = t; j < m; j += 512) {
        int b = sbkt[j];
        pairs[gbase[b] + (j - lbase[b])] = sorted[j];
    }
}

// Per-bucket degree histogram -> dinv. Replaces bfill.
__global__ __launch_bounds__(1024) void k_deg(const unsigned* __restrict__ pairs,
                                              const int* __restrict__ btot,
                                              float* __restrict__ dinv, int N) {
    __shared__ int deg[BSZ];
    int b = blockIdx.x;
    int t = threadIdx.x;
    if (t < BSZ) deg[t] = 0;
    __syncthreads();
    int m = btot[b];
    const unsigned* pb = pairs + (size_t)b * CAP;
    for (int i = t; i < m; i += 1024) atomicAdd(&deg[pb[i] >> 24], 1);
    __syncthreads();
    if (t < BSZ) {
        int v = (b << BSH) + t;
        if (v < N) dinv[v] = rsqrtf((float)deg[t]);  // deg >= 1 (self loop)
    }
}

// Solo gemm kernel (layer 2): H = (abuf @ W2) unscaled.
template <bool BF16IN>
__global__ __launch_bounds__(256) void k_gemm(const void* __restrict__ Xv,
                                              const float* __restrict__ W,
                                              unsigned* __restrict__ Hout,
                                              int N, int nSlabs, int nBlk) {
    __shared__ float SMEM[4224];
    gemm_body<BF16IN, 256>(Xv, W, Hout, N, nSlabs, blockIdx.x, nBlk, SMEM);
}

// Block-per-bucket aggregation with LDS accumulators.
// out[v] = epi( dinv[v] * sum_{(r,v) in bucket} dinv[r]*H[r] + bias )
// acc stride 65 floats/node -> ~2-way LDS bank conflicts on ds_add_f32.
template <bool RELU_BF16OUT>
__global__ __launch_bounds__(1024, 1) void k_agg(const unsigned* __restrict__ pairs,
                                                 const int* __restrict__ btot,
                                                 const float* __restrict__ dinv,
                                                 const uint4* __restrict__ H,
                                                 const float* __restrict__ bias,
                                                 void* __restrict__ outv, int N) {
    __shared__ float acc[BSZ * 65];  // 66,560 B
    int b = blockIdx.x;
    int t = threadIdx.x;
    int fl = t & 7;        // feature slice: feats 8*fl..8*fl+7
    int grp = t >> 3;      // edge group 0..127
    for (int i = t; i < BSZ * 65; i += 1024) acc[i] = 0.f;
    __syncthreads();
    int m = btot[b];
    const unsigned* pb = pairs + (size_t)b * CAP;
    const char* hb = (const char*)H + ((unsigned)fl << 4);

#define LACC(A, DD, D) do {                                                  \
        atomicAdd((A) + 0, (D) * bf16_lo((DD).x));                           \
        atomicAdd((A) + 1, (D) * bf16_hi((DD).x));                           \
        atomicAdd((A) + 2, (D) * bf16_lo((DD).y));                           \
        atomicAdd((A) + 3, (D) * bf16_hi((DD).y));                           \
        atomicAdd((A) + 4, (D) * bf16_lo((DD).z));                           \
        atomicAdd((A) + 5, (D) * bf16_hi((DD).z));                           \
        atomicAdd((A) + 6, (D) * bf16_lo((DD).w));                           \
        atomicAdd((A) + 7, (D) * bf16_hi((DD).w));                           \
    } while (0)

    int i = grp;
    if (i < m) {
        unsigned pk = pb[i];
        int r = (int)(pk & 0xFFFFFFu);
        float ds = dinv[r];
        uint4 hrow = *(const uint4*)(hb + ((size_t)(unsigned)r << 7));
        for (;;) {
            int ni = i + 128;
            if (ni < m) {                    // 1-deep pipeline
                unsigned npk = pb[ni];
                int nr = (int)(npk & 0xFFFFFFu);
                float nds = dinv[nr];
                uint4 nhrow = *(const uint4*)(hb + ((size_t)(unsigned)nr << 7));
                float* a = acc + (pk >> 24) * 65 + fl * 8;
                LACC(a, hrow, ds);
                i = ni; pk = npk; ds = nds; hrow = nhrow;
            } else {
                float* a = acc + (pk >> 24) * 65 + fl * 8;
                LACC(a, hrow, ds);
                break;
            }
        }
    }
#undef LACC
    __syncthreads();

    // Writeout: 4 threads per node, 16 feats each. Coalesced 128B/256B rows.
    int n = t >> 2;
    int l = t & 3;
    int v = (b << BSH) + n;
    if (v < N) {
        float dv = dinv[v];
        const float* a = acc + n * 65 + l * 16;
        const float4* b4 = (const float4*)bias;
        float4 bb0 = b4[l * 4 + 0];
        float4 bb1 = b4[l * 4 + 1];
        float4 bb2 = b4[l * 4 + 2];
        float4 bb3 = b4[l * 4 + 3];
        float r0  = fmaf(dv, a[0],  bb0.x), r1  = fmaf(dv, a[1],  bb0.y);
        float r2  = fmaf(dv, a[2],  bb0.z), r3  = fmaf(dv, a[3],  bb0.w);
        float r4  = fmaf(dv, a[4],  bb1.x), r5  = fmaf(dv, a[5],  bb1.y);
        float r6  = fmaf(dv, a[6],  bb1.z), r7  = fmaf(dv, a[7],  bb1.w);
        float r8  = fmaf(dv, a[8],  bb2.x), r9  = fmaf(dv, a[9],  bb2.y);
        float r10 = fmaf(dv, a[10], bb2.z), r11 = fmaf(dv, a[11], bb2.w);
        float r12 = fmaf(dv, a[12], bb3.x), r13 = fmaf(dv, a[13], bb3.y);
        float r14 = fmaf(dv, a[14], bb3.z), r15 = fmaf(dv, a[15], bb3.w);
        if (RELU_BF16OUT) {
            r0  = fmaxf(r0, 0.f);  r1  = fmaxf(r1, 0.f);
            r2  = fmaxf(r2, 0.f);  r3  = fmaxf(r3, 0.f);
            r4  = fmaxf(r4, 0.f);  r5  = fmaxf(r5, 0.f);
            r6  = fmaxf(r6, 0.f);  r7  = fmaxf(r7, 0.f);
            r8  = fmaxf(r8, 0.f);  r9  = fmaxf(r9, 0.f);
            r10 = fmaxf(r10, 0.f); r11 = fmaxf(r11, 0.f);
            r12 = fmaxf(r12, 0.f); r13 = fmaxf(r13, 0.f);
            r14 = fmaxf(r14, 0.f); r15 = fmaxf(r15, 0.f);
            uint4 p0, p1;
            p0.x = bf16_rne(r0)  | (bf16_rne(r1)  << 16);
            p0.y = bf16_rne(r2)  | (bf16_rne(r3)  << 16);
            p0.z = bf16_rne(r4)  | (bf16_rne(r5)  << 16);
            p0.w = bf16_rne(r6)  | (bf16_rne(r7)  << 16);
            p1.x = bf16_rne(r8)  | (bf16_rne(r9)  << 16);
            p1.y = bf16_rne(r10) | (bf16_rne(r11) << 16);
            p1.z = bf16_rne(r12) | (bf16_rne(r13) << 16);
            p1.w = bf16_rne(r14) | (bf16_rne(r15) << 16);
            uint4* dst = (uint4*)outv + (size_t)v * 8 + l * 2;
            dst[0] = p0;
            dst[1] = p1;
        } else {
            float4* o = (float4*)outv + (size_t)v * 16 + l * 4;
            o[0] = make_float4(r0,  r1,  r2,  r3);
            o[1] = make_float4(r4,  r5,  r6,  r7);
            o[2] = make_float4(r8,  r9,  r10, r11);
            o[3] = make_float4(r12, r13, r14, r15);
        }
    }
}

extern "C" void kernel_launch(void* const* d_in, const int* in_sizes, int n_in,
                              void* d_out, int out_size, void* d_ws, size_t ws_size,
                              hipStream_t stream) {
    const float* x  = (const float*)d_in[0];
    const int*   ei = (const int*)d_in[1];  // harness delivers int32
    const float* W1 = (const float*)d_in[2];
    const float* b1 = (const float*)d_in[3];
    const float* W2 = (const float*)d_in[4];
    const float* b2 = (const float*)d_in[5];
    float* out      = (float*)d_out;

    const int N = in_sizes[0] / 64;
    const int E = in_sizes[1] / 2;
    const int* row = ei;
    const int* col = ei + E;
    const int T = E + N;
    const int NB = (N + BSZ - 1) >> BSH;
    const int numTiles = (T + PTILE - 1) / PTILE;

    char* p = (char*)d_ws;
    auto alloc = [&](size_t bytes) { void* r = (void*)p; p += (bytes + 255) & ~(size_t)255; return r; };
    int*      tcnt    = (int*)alloc((size_t)NB * numTiles * 4);
    int*      btot    = (int*)alloc((size_t)(NB + 1) * 4);
    float*    dinv    = (float*)alloc((size_t)(N + 16) * 4);
    unsigned* pairs   = (unsigned*)alloc((size_t)NB * CAP * 4);
    unsigned* hbuf    = (unsigned*)alloc((size_t)(N + 16) * 32 * 4);  // bf16, +zero row
    unsigned* abuf    = (unsigned*)alloc((size_t)(N + 16) * 32 * 4);  // bf16

    const int nSlabs = (N + 16) / 16;  // covers zero sentinel row N

    k_cntgm<<<numTiles + GEMMB, 512, 0, stream>>>(col, E, N, NB, numTiles, tcnt,
                                                  x, W1, hbuf, nSlabs);
    k_scan<<<NB, 512, 0, stream>>>(tcnt, btot, NB, numTiles);
    k_scatter<<<numTiles, 512, 0, stream>>>(row, col, E, N, NB, numTiles, tcnt, pairs);
    k_deg<<<NB, 1024, 0, stream>>>(pairs, btot, dinv, N);

    k_agg<true><<<NB, 1024, 0, stream>>>(pairs, btot, dinv, (const uint4*)hbuf, b1, abuf, N);
    k_gemm<true><<<1024, 256, 0, stream>>>(abuf, W2, hbuf, N, nSlabs, 1024);
    k_agg<false><<<NB, 1024, 0, stream>>>(pairs, btot, dinv, (const uint4*)hbuf, b2, out, N);
}

// Round 12
// 196.979 us; speedup vs baseline: 8.0104x; 8.0104x over previous
//
#include <hip/hip_runtime.h>

// ---------------------------------------------------------------------------
// GCN 2-layer forward, round 24 = RESTORE of round-17 session best (197.96us).
// Round-23 post-mortem: CATASTROPHIC 1578us. LDS-atomic agg = 733us/dispatch
// with all pipes idle -> LDS float atomicAdd lowers to a CAS retry loop (not
// native ds_add_f32) and ~17 concurrent writers/node serialize; plus 391-block
// grid (1.5/CU) starved gather MLP. Design dead.
// Session summary of the ~198us plateau (all tested, all null/worse):
//   - launch fusion: cooperative (crash), manual barrier (-3x: TLP-starved
//     agg), parallel block-split + launch trim (neutral 200.2).
//   - agg divergence: degree-sorted perm (+20us: write de-coalescing).
//   - agg MLP: 2->4-8 rows in flight (null twice) -> agg is bound by the
//     L3/fabric random-gather service rate (~2.25TB/s over ~90MB/pass,
//     structurally irreducible: each H row needed by ~7.1 of 8 XCD L2s).
//   - CSR deletion via LDS-atomic accumulation (18x regression).
// Convicted budget: agg 2x~40us (fabric wall) + partition ~25 + bfill ~15
// + gemm ~12 + launch/ramp ~40. This restore is the final state.
// Pipeline: count, scan, scatter, bfill, gemm1, agg1, gemm2, agg2.
// ---------------------------------------------------------------------------

#define NPB 32       // nodes per block (agg): 256 thr / 8-lane groups
#define BSH 8        // bucket shift: 256 nodes per bucket
#define BSZ 256
#define PTILE 4096   // messages per partition tile
#define CAP 6144     // fixed bucket capacity (slots), multiple of 16
#define PADALLOW 3856  // per-bucket csrc pad allowance (256*15 + 16)
#define CROW (CAP + PADALLOW)  // per-bucket csrc region

typedef __attribute__((ext_vector_type(8))) short bf16x8;
typedef __attribute__((ext_vector_type(4))) float f32x4;

__device__ __forceinline__ unsigned bf16_rne(float f) {
    unsigned b = __float_as_uint(f);
    return (b + 0x7fffu + ((b >> 16) & 1u)) >> 16;
}
__device__ __forceinline__ float bf16_lo(unsigned u) { return __uint_as_float(u << 16); }
__device__ __forceinline__ float bf16_hi(unsigned u) { return __uint_as_float(u & 0xffff0000u); }

// Per-tile bucket histogram. tcnt layout: [tile][bucket] (tile-major ->
// contiguous writes here, contiguous cursor loads in k_scatter).
__global__ __launch_bounds__(512) void k_count(const int* __restrict__ coli,
                                               int E, int N, int NB, int numTiles,
                                               int* __restrict__ tcnt) {
    __shared__ int hist[512];
    int t = threadIdx.x;
    int T = E + N;
    int tile = blockIdx.x;
    int tstart = tile * PTILE;
    int m = min(PTILE, T - tstart);
    for (int b = t; b < NB; b += 512) hist[b] = 0;
    __syncthreads();
    for (int i = t; i < m; i += 512) {
        int g = tstart + i;
        int c = (g < E) ? coli[g] : (g - E);
        atomicAdd(&hist[c >> BSH], 1);
    }
    __syncthreads();
    for (int b = t; b < NB; b += 512) tcnt[(size_t)tile * NB + b] = hist[b];
}

// Block-per-bucket exclusive scan over tiles (chunked, wave-shuffle).
// tcnt[tile][b] <- b*CAP + prefix; btot[b] = bucket total.
__global__ __launch_bounds__(512) void k_scan(int* __restrict__ tcnt,
                                              int* __restrict__ btot,
                                              int NB, int numTiles) {
    __shared__ int wsum[8];
    int b = blockIdx.x;
    int t = threadIdx.x;
    int lane = t & 63, wid = t >> 6;
    int base = 0;
    for (int c0 = 0; c0 < numTiles; c0 += 512) {
        int tt = c0 + t;
        int v = (tt < numTiles) ? tcnt[(size_t)tt * NB + b] : 0;
        int inc = v;
        #pragma unroll
        for (int d = 1; d < 64; d <<= 1) {
            int o = __shfl_up(inc, d);
            if (lane >= d) inc += o;
        }
        if (lane == 63) wsum[wid] = inc;
        __syncthreads();
        int woff = 0, ctot = 0;
        #pragma unroll
        for (int i = 0; i < 8; i++) {
            int s = wsum[i];
            if (i < wid) woff += s;
            ctot += s;
        }
        if (tt < numTiles) tcnt[(size_t)tt * NB + b] = b * CAP + base + woff + inc - v;
        base += ctot;
        __syncthreads();  // wsum reused next chunk
    }
    if (t == 0) btot[b] = base;
}

// Scatter pass: LDS counting sort per tile, then COALESCED pairs writes.
// hist -> block scan (lbase) -> place into LDS sorted[] -> stream out in
// position order (consecutive lanes hit consecutive slots of a bucket chunk).
__global__ __launch_bounds__(512) void k_scatter(const int* __restrict__ rowi,
                                                 const int* __restrict__ coli,
                                                 int E, int N, int NB, int numTiles,
                                                 const int* __restrict__ tcnt,
                                                 unsigned* __restrict__ pairs) {
    __shared__ int hist[512];            // counts, then local cursors
    __shared__ int lbase[512];           // local exclusive base per bucket
    __shared__ int gbase[512];           // global base per bucket (tcnt row)
    __shared__ unsigned sorted[PTILE];   // payloads in tile-sorted order
    __shared__ unsigned short sbkt[PTILE];  // bucket id per sorted slot
    __shared__ int wsum[8];
    int t = threadIdx.x;
    int T = E + N;
    int tile = blockIdx.x;
    int tstart = tile * PTILE;
    int m = min(PTILE, T - tstart);
    for (int b = t; b < NB; b += 512) {
        hist[b] = 0;
        gbase[b] = tcnt[(size_t)tile * NB + b];
    }
    __syncthreads();
    int c_reg[8];  // statically indexed (rule: no runtime-indexed reg arrays)
    #pragma unroll
    for (int k = 0; k < 8; k++) {
        int i = t + k * 512;
        int c = 0;
        if (i < m) {
            int g = tstart + i;
            c = (g < E) ? coli[g] : (g - E);
            atomicAdd(&hist[c >> BSH], 1);
        }
        c_reg[k] = c;
    }
    __syncthreads();
    // block exclusive scan over NB (<=512) bucket counts -> lbase
    {
        int lane = t & 63, wid = t >> 6;
        int v = (t < NB) ? hist[t] : 0;
        int inc = v;
        #pragma unroll
        for (int d = 1; d < 64; d <<= 1) {
            int o = __shfl_up(inc, d);
            if (lane >= d) inc += o;
        }
        if (lane == 63) wsum[wid] = inc;
        __syncthreads();
        int woff = 0;
        for (int i = 0; i < wid; i++) woff += wsum[i];
        if (t < NB) lbase[t] = woff + inc - v;
        __syncthreads();
    }
    for (int b = t; b < NB; b += 512) hist[b] = 0;  // reuse as cursors
    __syncthreads();
    #pragma unroll
    for (int k = 0; k < 8; k++) {
        int i = t + k * 512;
        if (i < m) {
            int g = tstart + i;
            int c = c_reg[k];
            int r = (g < E) ? rowi[g] : c;  // self-loop tail has r == c
            int b = c >> BSH;
            int lr = atomicAdd(&hist[b], 1);
            int pos = lbase[b] + lr;
            sorted[pos] = (unsigned)r | ((unsigned)(c & (BSZ - 1)) << 24);
            sbkt[pos] = (unsigned short)b;
        }
    }
    __syncthreads();
    for (int j = t; j < m; j += 512) {
        int b = sbkt[j];
        pairs[gbase[b] + (j - lbase[b])] = sorted[j];
    }
}

// One block per bucket (1024 threads): histogram its <=256 nodes, scan PADDED
// counts, build the ENTIRE padded csrc region in LDS (payload + sentinel
// pads), then one coalesced LDS->global copy. CSR meta as before.
__global__ __launch_bounds__(1024) void k_bfill(const unsigned* __restrict__ pairs,
                                                const int* __restrict__ btot,
                                                int N,
                                                int* __restrict__ offsets,
                                                int* __restrict__ cnt,
                                                float* __restrict__ dinv,
                                                int* __restrict__ csrc) {
    __shared__ int scnt[BSZ];
    __shared__ int scur[BSZ];
    __shared__ int wsum[4];
    __shared__ int scsrc[CROW];  // 40KB: full padded bucket region
    int b = blockIdx.x;
    int t = threadIdx.x;
    int ebeg = b * CAP;
    int m = btot[b];
    int pbase = b * CROW;  // 16-aligned per-bucket csrc region base
    int lane = t & 63, wid = t >> 6;
    if (t < BSZ) scnt[t] = 0;
    __syncthreads();
    for (int i = t; i < m; i += 1024) {
        atomicAdd(&scnt[pairs[ebeg + i] >> 24], 1);
    }
    __syncthreads();
    int cval = 0, pc = 0, inc = 0;
    if (t < BSZ) {
        cval = scnt[t];                 // true msg count (incl. self loop)
        pc = (cval + 15) & ~15;         // padding: multiple of 16
        inc = pc;
        #pragma unroll
        for (int d = 1; d < 64; d <<= 1) {
            int o = __shfl_up(inc, d);
            if (lane >= d) inc += o;
        }
        if (lane == 63) wsum[wid] = inc;
    }
    __syncthreads();
    if (t < BSZ) {
        int woff = 0;
        for (int i = 0; i < wid; i++) woff += wsum[i];
        int offl = woff + inc - pc;         // LOCAL padded offset
        int v = (b << BSH) + t;
        if (v < N) {
            offsets[v] = pbase + offl;
            cnt[v] = (cval + 1) & ~1;       // round to x2 for int2 agg loop
            dinv[v] = rsqrtf((float)cval);  // cval >= 1 (self loop)
        }
        scur[t] = offl;
        // sentinel pads (read H row N == zeros) -- in LDS
        for (int i = offl + cval; i < offl + pc; i++) scsrc[i] = N;
    }
    __syncthreads();
    for (int i = t; i < m; i += 1024) {
        unsigned pk = pairs[ebeg + i];
        int slot = atomicAdd(&scur[pk >> 24], 1);
        scsrc[slot] = (int)(pk & 0xFFFFFFu);
    }
    __syncthreads();
    int tot = wsum[0] + wsum[1] + wsum[2] + wsum[3];  // total padded length
    for (int j = t; j < tot; j += 1024) csrc[pbase + j] = scsrc[j];
}

// H[row] = dinv[row] * (X[row] @ W) via mfma_f32_16x16x32_bf16.
// Also writes an all-zero row at index N (sentinel target for csrc pads).
template <bool BF16IN>
__global__ __launch_bounds__(256) void k_gemm(const void* __restrict__ Xv,
                                              const float* __restrict__ W,
                                              const float* __restrict__ dinv,
                                              unsigned* __restrict__ Hout,
                                              int N, int nSlabs, int slabStride) {
    __shared__ float SMEM[4224];  // 4096 W staging, then 4 x (16x66) transpose
    int t = threadIdx.x;
    int lane = t & 63, w = t >> 6;
    int nn = lane & 15, kq = lane >> 4;

    for (int i = t; i < 1024; i += 256) ((float4*)SMEM)[i] = ((const float4*)W)[i];
    __syncthreads();
    bf16x8 Bf[2][4];
    #pragma unroll
    for (int kt = 0; kt < 2; kt++) {
        #pragma unroll
        for (int ct = 0; ct < 4; ct++) {
            union { bf16x8 v; unsigned short s[8]; } u;
            #pragma unroll
            for (int j = 0; j < 8; j++) {
                int k = kt * 32 + kq * 8 + j;
                u.s[j] = (unsigned short)bf16_rne(SMEM[k * 64 + ct * 16 + nn]);
            }
            Bf[kt][ct] = u.v;
        }
    }
    __syncthreads();  // W region dead; SMEM becomes transpose scratch

    float* outT = SMEM + w * 1056;  // 16 rows x 66 floats

    for (int slab = blockIdx.x * 4 + w; slab < nSlabs; slab += slabStride) {
        int row0 = slab * 16;
        int rowA = min(row0 + nn, N - 1);
        bf16x8 A0, A1;
        if (BF16IN) {
            const uint4* X = (const uint4*)Xv;  // row = 8 uint4
            union { uint4 u; bf16x8 v; } a0, a1;
            a0.u = X[(size_t)rowA * 8 + kq];
            a1.u = X[(size_t)rowA * 8 + 4 + kq];
            A0 = a0.v; A1 = a1.v;
        } else {
            const float4* X = (const float4*)Xv;  // row = 16 float4
            float4 f0 = X[(size_t)rowA * 16 + kq * 2];
            float4 f1 = X[(size_t)rowA * 16 + kq * 2 + 1];
            float4 f2 = X[(size_t)rowA * 16 + 8 + kq * 2];
            float4 f3 = X[(size_t)rowA * 16 + 8 + kq * 2 + 1];
            union { bf16x8 v; unsigned short s[8]; } a0, a1;
            a0.s[0] = (unsigned short)bf16_rne(f0.x); a0.s[1] = (unsigned short)bf16_rne(f0.y);
            a0.s[2] = (unsigned short)bf16_rne(f0.z); a0.s[3] = (unsigned short)bf16_rne(f0.w);
            a0.s[4] = (unsigned short)bf16_rne(f1.x); a0.s[5] = (unsigned short)bf16_rne(f1.y);
            a0.s[6] = (unsigned short)bf16_rne(f1.z); a0.s[7] = (unsigned short)bf16_rne(f1.w);
            a1.s[0] = (unsigned short)bf16_rne(f2.x); a1.s[1] = (unsigned short)bf16_rne(f2.y);
            a1.s[2] = (unsigned short)bf16_rne(f2.z); a1.s[3] = (unsigned short)bf16_rne(f2.w);
            a1.s[4] = (unsigned short)bf16_rne(f3.x); a1.s[5] = (unsigned short)bf16_rne(f3.y);
            a1.s[6] = (unsigned short)bf16_rne(f3.z); a1.s[7] = (unsigned short)bf16_rne(f3.w);
            A0 = a0.v; A1 = a1.v;
        }
        float dvm = dinv[rowA];

        f32x4 acc[4];
        #pragma unroll
        for (int ct = 0; ct < 4; ct++) acc[ct] = (f32x4){0.f, 0.f, 0.f, 0.f};
        #pragma unroll
        for (int ct = 0; ct < 4; ct++) {
            acc[ct] = __builtin_amdgcn_mfma_f32_16x16x32_bf16(A0, Bf[0][ct], acc[ct], 0, 0, 0);
            acc[ct] = __builtin_amdgcn_mfma_f32_16x16x32_bf16(A1, Bf[1][ct], acc[ct], 0, 0, 0);
        }

        #pragma unroll
        for (int reg = 0; reg < 4; reg++) {
            int r = kq * 4 + reg;
            float dv = __shfl(dvm, r);  // lane r holds dinv[row0+r]
            #pragma unroll
            for (int ct = 0; ct < 4; ct++) {
                outT[r * 66 + ct * 16 + nn] = acc[ct][reg] * dv;
            }
        }
        int rr = lane >> 2;        // 4 lanes per row
        int c0 = (lane & 3) * 16;  // 16 cols per lane
        int orow = row0 + rr;
        if (orow < N) {
            unsigned pk[8];
            #pragma unroll
            for (int i = 0; i < 8; i++) {
                float lo = outT[rr * 66 + c0 + 2 * i];
                float hi = outT[rr * 66 + c0 + 2 * i + 1];
                pk[i] = bf16_rne(lo) | (bf16_rne(hi) << 16);
            }
            uint4* dst = (uint4*)Hout + (size_t)orow * 8 + (lane & 3) * 2;
            dst[0] = make_uint4(pk[0], pk[1], pk[2], pk[3]);
            dst[1] = make_uint4(pk[4], pk[5], pk[6], pk[7]);
        } else if (orow == N) {  // zero sentinel row
            uint4* dst = (uint4*)Hout + (size_t)N * 8 + (lane & 3) * 2;
            dst[0] = make_uint4(0, 0, 0, 0);
            dst[1] = make_uint4(0, 0, 0, 0);
        }
    }
}

// out[v] = epi( dinv[v] * sum_{j in CSR[v]} H[src_j] + bias )
// One node per 8-lane group (8 nodes per wave, 32 per block).
template <bool RELU_BF16OUT>
__global__ __launch_bounds__(256) void k_agg(const uint4* __restrict__ H,
                                             const int* __restrict__ offsets,
                                             const int* __restrict__ cnt,
                                             const int* __restrict__ csrc,
                                             const float* __restrict__ dinv,
                                             const float* __restrict__ bias,
                                             void* __restrict__ outv, int N) {
    int t = threadIdx.x;
    int fl = t & 7;                       // feature group: feats 8*fl..8*fl+7
    int v = blockIdx.x * NPB + (t >> 3);
    if (v >= N) return;
    int beg = offsets[v];                 // 16-aligned
    int deg = cnt[v];                     // true count rounded up to x2
    const int2* cs2 = (const int2*)(csrc + beg);
    const char* hb = (const char*)H + ((unsigned)fl << 4);

    float a0 = 0.f, a1 = 0.f, a2 = 0.f, a3 = 0.f;
    float a4 = 0.f, a5 = 0.f, a6 = 0.f, a7 = 0.f;

#define ACC8(R) do {                                                        \
        uint4 dd = *(const uint4*)(hb + ((unsigned)(R) << 7));              \
        a0 += bf16_lo(dd.x); a1 += bf16_hi(dd.x);                           \
        a2 += bf16_lo(dd.y); a3 += bf16_hi(dd.y);                           \
        a4 += bf16_lo(dd.z); a5 += bf16_hi(dd.z);                           \
        a6 += bf16_lo(dd.w); a7 += bf16_hi(dd.w);                           \
    } while (0)

    int2 ss = cs2[0];                     // deg >= 2 always (self loop + pad)
    for (int j = 2; j < deg; j += 2) {
        int2 nx = cs2[j >> 1];            // independent: issues before adds
        ACC8(ss.x);
        ACC8(ss.y);
        ss = nx;
    }
    ACC8(ss.x);
    ACC8(ss.y);
#undef ACC8

    float dv = dinv[v];
    const float4* b4 = (const float4*)bias;
    float4 bA = b4[fl * 2];
    float4 bB = b4[fl * 2 + 1];
    float r0 = fmaf(dv, a0, bA.x);
    float r1 = fmaf(dv, a1, bA.y);
    float r2 = fmaf(dv, a2, bA.z);
    float r3 = fmaf(dv, a3, bA.w);
    float r4 = fmaf(dv, a4, bB.x);
    float r5 = fmaf(dv, a5, bB.y);
    float r6 = fmaf(dv, a6, bB.z);
    float r7 = fmaf(dv, a7, bB.w);
    if (RELU_BF16OUT) {
        r0 = fmaxf(r0, 0.f); r1 = fmaxf(r1, 0.f);
        r2 = fmaxf(r2, 0.f); r3 = fmaxf(r3, 0.f);
        r4 = fmaxf(r4, 0.f); r5 = fmaxf(r5, 0.f);
        r6 = fmaxf(r6, 0.f); r7 = fmaxf(r7, 0.f);
        uint4 pk;
        pk.x = bf16_rne(r0) | (bf16_rne(r1) << 16);
        pk.y = bf16_rne(r2) | (bf16_rne(r3) << 16);
        pk.z = bf16_rne(r4) | (bf16_rne(r5) << 16);
        pk.w = bf16_rne(r6) | (bf16_rne(r7) << 16);
        ((uint4*)outv)[(size_t)v * 8 + fl] = pk;
    } else {
        float4* o = (float4*)outv + (size_t)v * 16 + fl * 2;
        o[0] = make_float4(r0, r1, r2, r3);
        o[1] = make_float4(r4, r5, r6, r7);
    }
}

extern "C" void kernel_launch(void* const* d_in, const int* in_sizes, int n_in,
                              void* d_out, int out_size, void* d_ws, size_t ws_size,
                              hipStream_t stream) {
    const float* x  = (const float*)d_in[0];
    const int*   ei = (const int*)d_in[1];  // harness delivers int32
    const float* W1 = (const float*)d_in[2];
    const float* b1 = (const float*)d_in[3];
    const float* W2 = (const float*)d_in[4];
    const float* b2 = (const float*)d_in[5];
    float* out      = (float*)d_out;

    const int N = in_sizes[0] / 64;
    const int E = in_sizes[1] / 2;
    const int* row = ei;
    const int* col = ei + E;
    const int T = E + N;
    const int NB = (N + BSZ - 1) >> BSH;  // buckets
    const int numTiles = (T + PTILE - 1) / PTILE;

    char* p = (char*)d_ws;
    auto alloc = [&](size_t bytes) { void* r = (void*)p; p += (bytes + 255) & ~(size_t)255; return r; };
    int*      tcnt    = (int*)alloc((size_t)NB * numTiles * 4);
    int*      btot    = (int*)alloc((size_t)(NB + 1) * 4);
    int*      offsets = (int*)alloc((size_t)N * 4);
    int*      cnt     = (int*)alloc((size_t)N * 4);
    float*    dinv    = (float*)alloc((size_t)N * 4);
    unsigned* pairs   = (unsigned*)alloc((size_t)NB * CAP * 4);
    int*      csrc    = (int*)alloc(((size_t)NB * CROW + 64) * 4);
    unsigned* hbuf    = (unsigned*)alloc((size_t)(N + 16) * 32 * 4);  // bf16, +zero row
    unsigned* abuf    = (unsigned*)alloc((size_t)(N + 16) * 32 * 4);  // bf16, +zero row

    k_count<<<numTiles, 512, 0, stream>>>(col, E, N, NB, numTiles, tcnt);
    k_scan<<<NB, 512, 0, stream>>>(tcnt, btot, NB, numTiles);
    k_scatter<<<numTiles, 512, 0, stream>>>(row, col, E, N, NB, numTiles, tcnt, pairs);
    k_bfill<<<NB, 1024, 0, stream>>>(pairs, btot, N, offsets, cnt, dinv, csrc);

    const int nSlabs = (N + 16) / 16;  // covers zero sentinel row N
    const int GEMM_BLOCKS = 1024;
    const int SLAB_STRIDE = GEMM_BLOCKS * 4;
    const int GB = (N + NPB - 1) / NPB;

    k_gemm<false><<<GEMM_BLOCKS, 256, 0, stream>>>(x, W1, dinv, hbuf, N, nSlabs, SLAB_STRIDE);
    k_agg<true><<<GB, 256, 0, stream>>>((const uint4*)hbuf, offsets, cnt, csrc, dinv, b1, abuf, N);
    k_gemm<true><<<GEMM_BLOCKS, 256, 0, stream>>>(abuf, W2, dinv, hbuf, N, nSlabs, SLAB_STRIDE);
    k_agg<false><<<GB, 256, 0, stream>>>((const uint4*)hbuf, offsets, cnt, csrc, dinv, b2, out, N);
}